// Round 7
// baseline (530.723 us; speedup 1.0000x reference)
//
#include <hip/hip_runtime.h>
#include <stdint.h>

typedef __bf16 bf16;
typedef __bf16 bf16x8 __attribute__((ext_vector_type(8)));
typedef __bf16 bf16x4 __attribute__((ext_vector_type(4)));
typedef float  f32x4  __attribute__((ext_vector_type(4)));

#define AS1 __attribute__((address_space(1)))
#define AS3 __attribute__((address_space(3)))

// async global->LDS, 16B per lane; LDS dest is wave-uniform base + lane*16B
__device__ __forceinline__ void gload16(void* l, const void* g) {
  __builtin_amdgcn_global_load_lds((AS1 void*)(g), (AS3 void*)(l), 16, 0, 0);
}

#define NB 4
#define TT 2048
#define CC 1024
#define HH 16
#define DD 64
#define DHID 4096
#define MM (NB*TT)   // 8192

#define SBAR()  asm volatile("s_barrier" ::: "memory")
#define LGKM0() do { asm volatile("s_waitcnt lgkmcnt(0)" ::: "memory"); \
                     __builtin_amdgcn_sched_barrier(0); } while (0)

// ---------------- weight fp32 -> bf16 convert ----------------
__global__ __launch_bounds__(256)
void cvt_kernel(const float* __restrict__ wq, const float* __restrict__ wk,
                const float* __restrict__ wvv, const float* __restrict__ f1,
                const float* __restrict__ f2, bf16* __restrict__ dst) {
  const int NCH = 2883584;  // 11,534,336 elems / 4
  for (int ch = blockIdx.x*256 + threadIdx.x; ch < NCH; ch += gridDim.x*256) {
    const float* s; int base;
    if (ch < 262144)       { s = wq;  base = 0; }
    else if (ch < 524288)  { s = wk;  base = 262144; }
    else if (ch < 786432)  { s = wvv; base = 524288; }
    else if (ch < 1835008) { s = f1;  base = 786432; }
    else                   { s = f2;  base = 1835008; }
    float4 v = ((const float4*)s)[ch - base];
    bf16x4 o = { (bf16)v.x, (bf16)v.y, (bf16)v.z, (bf16)v.w };
    *(bf16x4*)(dst + (size_t)ch*4) = o;
  }
}

// ---------------- fused layernorm -> bf16 ----------------
__global__ __launch_bounds__(256)
void ln_kernel(const float* __restrict__ x, const float* __restrict__ w,
               const float* __restrict__ b, bf16* __restrict__ out) {
  const int row = blockIdx.x;
  const int t = threadIdx.x;
  const float4 v = ((const float4*)(x + (size_t)row*CC))[t];
  float s  = v.x + v.y + v.z + v.w;
  float sq = v.x*v.x + v.y*v.y + v.z*v.z + v.w*v.w;
  #pragma unroll
  for (int m = 1; m < 64; m <<= 1) {
    s  += __shfl_xor(s, m, 64);
    sq += __shfl_xor(sq, m, 64);
  }
  __shared__ float red[8];
  const int wv = t >> 6;
  if ((t & 63) == 0) { red[wv] = s; red[4+wv] = sq; }
  __syncthreads();
  s  = red[0]+red[1]+red[2]+red[3];
  sq = red[4]+red[5]+red[6]+red[7];
  const float mu = s * (1.0f/CC);
  const float rs = rsqrtf(sq*(1.0f/CC) - mu*mu + 1e-5f);
  const float4 wv4 = ((const float4*)w)[t];
  const float4 bv4 = ((const float4*)b)[t];
  bf16x4 o = { (bf16)((v.x-mu)*rs*wv4.x + bv4.x),
               (bf16)((v.y-mu)*rs*wv4.y + bv4.y),
               (bf16)((v.z-mu)*rs*wv4.z + bv4.z),
               (bf16)((v.w-mu)*rs*wv4.w + bv4.w) };
  *(bf16x4*)(out + (size_t)row*CC + t*4) = o;
}

__device__ __forceinline__ float gelu_f(float x) {
  const float kC = 0.7978845608028654f;
  float z = kC * (x + 0.044715f * x*x*x);
  float e = __expf(2.0f*z);
  float th = 1.0f - 2.0f/(e + 1.0f);
  return 0.5f * x * (1.0f + th);
}

// ---------------- 8-phase GEMM: C[M,N] = A[M,K] @ B[N,K]^T ----------------
// BM=128, BN=256, BK=64. 512 thr (8 waves, 2M x 4N), wave tile 64x64.
// Per K-tile: 4 phases x 8 MFMA. Stage halves: B-h1@ph1->nxt, B-h0@ph3->cur,
// A@ph4->cur (each after its region's final ds_read + barrier). vmcnt(4)
// counted once per tile. LDS chunk-XOR swizzle, pre-swizzled global source.
template<int MODE>
__global__ __launch_bounds__(512, 2)
void gemm8_kernel(const bf16* __restrict__ A, const bf16* __restrict__ B, int K,
                  void* outp, const float* __restrict__ bias, const float* resid) {
  __shared__ __align__(16) bf16 Ab[2][128*64];   // 2 x 16KB
  __shared__ __align__(16) bf16 Bb[2][256*64];   // 2 x 32KB
  const int tid = threadIdx.x, lane = tid & 63, wv = tid >> 6;
  const int g = lane >> 4, c = lane & 15;
  const int wm = wv >> 2, wn = wv & 3;
  const int bm0 = blockIdx.x * 128, bn0 = blockIdx.y * 256;
  const int NT = K >> 6;

  // staging: lane covers row wv*8+(lane>>3) (+64 for 2nd gload), chunk lane&7
  const int lr = lane >> 3;
  const int sw8 = ((lane & 7) ^ lr) << 3;        // pre-swizzled k-chunk offset
  const bf16* sA  = A + (size_t)(bm0 + wv*8 + lr) * K + sw8;
  const bf16* sB0 = B + (size_t)(bn0 + wv*8 + lr) * K + sw8;
  const bf16* sB1 = sB0 + (size_t)128 * K;

  #define ST_A(b, tt)  do { \
      gload16(&Ab[b][wv*512],         sA  + (size_t)(tt)*64); \
      gload16(&Ab[b][4096 + wv*512],  sA  + (size_t)64*K + (size_t)(tt)*64); } while (0)
  #define ST_B0(b, tt) do { \
      gload16(&Bb[b][wv*512],         sB0 + (size_t)(tt)*64); \
      gload16(&Bb[b][4096 + wv*512],  sB0 + (size_t)64*K + (size_t)(tt)*64); } while (0)
  #define ST_B1(b, tt) do { \
      gload16(&Bb[b][8192 + wv*512],  sB1 + (size_t)(tt)*64); \
      gload16(&Bb[b][12288 + wv*512], sB1 + (size_t)64*K + (size_t)(tt)*64); } while (0)

  // prologue: t0 all halves, then t1.B-h0 + t1.A (t1.B-h1 staged at cycle0.ph1)
  ST_B0(0, 0); ST_B1(0, 0); ST_A(0, 0);
  ST_B0(1, 1); ST_A(1, 1);
  asm volatile("s_waitcnt vmcnt(4)" ::: "memory");
  SBAR();

  f32x4 acc[4][4] = {};
  const int ach0 = ((0*4 + g) ^ (c & 7)) << 3;   // kk=0 swizzled chunk byte/2
  const int ach1 = ((1*4 + g) ^ (c & 7)) << 3;   // kk=1

  int cur = 0;
  for (int kt = 0; kt < NT; ++kt) {
    const int nxt = cur ^ 1;
    const bool s1 = (kt + 1) < NT;
    const bool s2 = (kt + 2) < NT;
    bf16x8 af[2][2], bfv[4][2];

    // ---- ph1: quadrant (0,0). reads A ms0-1, B ns0-1. stage (t+1).B-h1 ----
    #pragma unroll
    for (int m2 = 0; m2 < 2; ++m2) {
      const int r = (wm*64 + m2*16 + c) * 64;
      af[m2][0] = *(const bf16x8*)&Ab[cur][r + ach0];
      af[m2][1] = *(const bf16x8*)&Ab[cur][r + ach1];
    }
    #pragma unroll
    for (int n2 = 0; n2 < 2; ++n2) {
      const int r = (wn*64 + n2*16 + c) * 64;
      bfv[n2][0] = *(const bf16x8*)&Bb[cur][r + ach0];
      bfv[n2][1] = *(const bf16x8*)&Bb[cur][r + ach1];
    }
    if (s1) ST_B1(nxt, kt + 1);
    SBAR(); LGKM0();
    __builtin_amdgcn_s_setprio(1);
    #pragma unroll
    for (int m2 = 0; m2 < 2; ++m2)
      #pragma unroll
      for (int n2 = 0; n2 < 2; ++n2)
        #pragma unroll
        for (int kk = 0; kk < 2; ++kk)
          acc[m2][n2] = __builtin_amdgcn_mfma_f32_16x16x32_bf16(
              af[m2][kk], bfv[n2][kk], acc[m2][n2], 0, 0, 0);
    __builtin_amdgcn_s_setprio(0);
    SBAR();

    // ---- ph2: quadrant (0,1). reads B ns2-3 ----
    #pragma unroll
    for (int n2 = 0; n2 < 2; ++n2) {
      const int r = (wn*64 + 32 + n2*16 + c) * 64;
      bfv[2+n2][0] = *(const bf16x8*)&Bb[cur][r + ach0];
      bfv[2+n2][1] = *(const bf16x8*)&Bb[cur][r + ach1];
    }
    SBAR(); LGKM0();
    __builtin_amdgcn_s_setprio(1);
    #pragma unroll
    for (int m2 = 0; m2 < 2; ++m2)
      #pragma unroll
      for (int n2 = 0; n2 < 2; ++n2)
        #pragma unroll
        for (int kk = 0; kk < 2; ++kk)
          acc[m2][2+n2] = __builtin_amdgcn_mfma_f32_16x16x32_bf16(
              af[m2][kk], bfv[2+n2][kk], acc[m2][2+n2], 0, 0, 0);
    __builtin_amdgcn_s_setprio(0);
    SBAR();

    // ---- ph3: quadrant (1,0). reads A ms2-3. stage (t+2).B-h0 -> cur ----
    #pragma unroll
    for (int m2 = 0; m2 < 2; ++m2) {
      const int r = (wm*64 + 32 + m2*16 + c) * 64;
      af[m2][0] = *(const bf16x8*)&Ab[cur][r + ach0];
      af[m2][1] = *(const bf16x8*)&Ab[cur][r + ach1];
    }
    if (s2) ST_B0(cur, kt + 2);
    SBAR(); LGKM0();
    __builtin_amdgcn_s_setprio(1);
    #pragma unroll
    for (int m2 = 0; m2 < 2; ++m2)
      #pragma unroll
      for (int n2 = 0; n2 < 2; ++n2)
        #pragma unroll
        for (int kk = 0; kk < 2; ++kk)
          acc[2+m2][n2] = __builtin_amdgcn_mfma_f32_16x16x32_bf16(
              af[m2][kk], bfv[n2][kk], acc[2+m2][n2], 0, 0, 0);
    __builtin_amdgcn_s_setprio(0);
    SBAR();

    // ---- ph4: quadrant (1,1), regs only. stage (t+2).A -> cur ----
    if (s2) ST_A(cur, kt + 2);
    __builtin_amdgcn_s_setprio(1);
    #pragma unroll
    for (int m2 = 0; m2 < 2; ++m2)
      #pragma unroll
      for (int n2 = 0; n2 < 2; ++n2)
        #pragma unroll
        for (int kk = 0; kk < 2; ++kk)
          acc[2+m2][2+n2] = __builtin_amdgcn_mfma_f32_16x16x32_bf16(
              af[m2][kk], bfv[2+n2][kk], acc[2+m2][2+n2], 0, 0, 0);
    __builtin_amdgcn_s_setprio(0);
    if (s2) asm volatile("s_waitcnt vmcnt(4)" ::: "memory");
    else    asm volatile("s_waitcnt vmcnt(0)" ::: "memory");
    SBAR();
    cur = nxt;
  }

  // epilogue: D layout col = lane&15, row = (lane>>4)*4 + reg
  #pragma unroll
  for (int ms = 0; ms < 4; ++ms) {
    const int m = bm0 + wm*64 + ms*16 + g*4;
    #pragma unroll
    for (int ns = 0; ns < 4; ++ns) {
      const int j = bn0 + wn*64 + ns*16 + c;
      if constexpr (MODE == 0) {
        const int which = j >> 10, hd = j & 1023;
        const int n_ = m >> 11, t_ = m & 2047;
        bf16* dst = (bf16*)outp + (size_t)which*(MM*CC)
                    + (((size_t)(n_*HH + (hd>>6))*TT + t_) << 6) + (hd & 63);
        #pragma unroll
        for (int jj = 0; jj < 4; ++jj)
          dst[(size_t)jj << 6] = (bf16)acc[ms][ns][jj];
      } else if constexpr (MODE == 1) {
        const float bb = bias[j];
        bf16* o = (bf16*)outp;
        #pragma unroll
        for (int jj = 0; jj < 4; ++jj)
          o[(size_t)(m+jj)*DHID + j] = (bf16)gelu_f(acc[ms][ns][jj] + bb);
      } else {
        const float bb = bias[j];
        float* o = (float*)outp;
        #pragma unroll
        for (int jj = 0; jj < 4; ++jj) {
          const size_t ix = (size_t)(m+jj)*CC + j;
          o[ix] = acc[ms][ns][jj] + bb + resid[ix];
        }
      }
    }
  }
  #undef ST_A
  #undef ST_B0
  #undef ST_B1
}

// ---------------- flash attention (causal, swapped-QK^T) + residual ----------------
__global__ __launch_bounds__(256)
void attn_kernel(const bf16* __restrict__ qkv, const float* __restrict__ x,
                 float* __restrict__ out) {
  __shared__ __align__(16) bf16 Kb[2][64*64];   // [key][d], chunk^=(key&7)
  __shared__ __align__(16) bf16 Vt[2][64*64];   // [d][key], chunk^=(d&7)^((d>>4)<<1)
  __shared__ __align__(16) bf16 Pb[4][32*64];   // per-wave [q][key], chunk^=(q&7)
  const int tid = threadIdx.x, lane = tid & 63, wv = tid >> 6;
  const int g = lane >> 4, c = lane & 15;
  const int nh = blockIdx.x >> 3, pr = blockIdx.x & 7;
  const int n = nh >> 4, h = nh & 15;
  const bf16* qp = qkv + (size_t)nh * (TT*DD);
  const bf16* kp = qp + (size_t)(MM*CC);
  const bf16* vp = qp + (size_t)(2*MM*CC);
  const float INVS = 0.125f * 1.4426950408889634f;  // 1/sqrt(64) * log2(e)

  const int krow0 = wv*8 + (lane >> 3), kch = lane & 7;
  const int krow1 = krow0 + 32;
  const int ksw0 = ((kch ^ (krow0 & 7)) << 3);
  const int ksw1 = ((kch ^ (krow1 & 7)) << 3);
  const int vkey = tid >> 2, vqd = tid & 3;

  #define VT_WRITE(buf)                                                      \
    do {                                                                     \
      _Pragma("unroll")                                                      \
      for (int j2 = 0; j2 < 16; ++j2) {                                      \
        const int d = vqd*16 + j2;                                           \
        const int ch = ((vkey >> 3) ^ (j2 & 7) ^ (vqd << 1)) & 7;            \
        Vt[buf][d*64 + (ch << 3) + (vkey & 7)] =                             \
            (j2 < 8) ? vr0[j2] : vr1[j2 - 8];                                \
      }                                                                      \
    } while (0)

  for (int half = 0; half < 2; ++half) {
    const int qt = half ? (15 - pr) : pr;
    const int q0w = qt*128 + wv*32;
    const int ktl = (q0w + 31) >> 6;
    const int nkt = 2*qt + 2;

    bf16x8 qf[2][2];
    #pragma unroll
    for (int qs = 0; qs < 2; ++qs)
      #pragma unroll
      for (int kk = 0; kk < 2; ++kk)
        qf[qs][kk] = *(const bf16x8*)(qp + (size_t)(q0w + qs*16 + c)*DD + kk*32 + g*8);

    f32x4 o[2][4] = {};
    float mrow[2] = {-1e30f, -1e30f};
    float lrow[2] = {0.f, 0.f};

    gload16(&Kb[0][wv*512],        kp + (size_t)krow0*DD + ksw0);
    gload16(&Kb[0][2048 + wv*512], kp + (size_t)krow1*DD + ksw1);
    bf16x8 vr0 = *(const bf16x8*)(vp + (size_t)vkey*DD + vqd*16);
    bf16x8 vr1 = *(const bf16x8*)(vp + (size_t)vkey*DD + vqd*16 + 8);
    asm volatile("s_waitcnt vmcnt(0)" ::: "memory");
    VT_WRITE(0);
    __syncthreads();

    int cur = 0;
    for (int kt = 0; kt < nkt; ++kt) {
      const int nxt = cur ^ 1;
      const bool hn = (kt + 1) < nkt;
      if (hn) {
        const size_t kb = (size_t)(kt + 1) * 64;
        gload16(&Kb[nxt][wv*512],        kp + (kb + krow0)*DD + ksw0);
        gload16(&Kb[nxt][2048 + wv*512], kp + (kb + krow1)*DD + ksw1);
        vr0 = *(const bf16x8*)(vp + (kb + vkey)*DD + vqd*16);
        vr1 = *(const bf16x8*)(vp + (kb + vkey)*DD + vqd*16 + 8);
        asm volatile("" :: "v"(vr0), "v"(vr1));
      }

      if (kt <= ktl) {
        f32x4 sa[4][2] = {};
        __builtin_amdgcn_s_setprio(1);
        #pragma unroll
        for (int ks = 0; ks < 4; ++ks) {
          #pragma unroll
          for (int kk = 0; kk < 2; ++kk) {
            const bf16x8 kf = *(const bf16x8*)
                &Kb[cur][(ks*16 + c)*64 + (((kk*4 + g) ^ (c & 7)) << 3)];
            #pragma unroll
            for (int qs = 0; qs < 2; ++qs)
              sa[ks][qs] = __builtin_amdgcn_mfma_f32_16x16x32_bf16(
                  kf, qf[qs][kk], sa[ks][qs], 0, 0, 0);
          }
        }
        __builtin_amdgcn_s_setprio(0);
        const bool diag = (kt == ktl);
        #pragma unroll
        for (int qs = 0; qs < 2; ++qs) {
          const int q = q0w + qs*16 + c;
          float p[4][4];
          #pragma unroll
          for (int ks = 0; ks < 4; ++ks)
            #pragma unroll
            for (int jj = 0; jj < 4; ++jj) {
              float sv = sa[ks][qs][jj] * INVS;
              if (diag && (kt*64 + ks*16 + g*4 + jj > q)) sv = -1e30f;
              p[ks][jj] = sv;
            }
          float tm = p[0][0];
          #pragma unroll
          for (int ks = 0; ks < 4; ++ks)
            #pragma unroll
            for (int jj = 0; jj < 4; ++jj) tm = fmaxf(tm, p[ks][jj]);
          tm = fmaxf(tm, __shfl_xor(tm, 16, 64));
          tm = fmaxf(tm, __shfl_xor(tm, 32, 64));
          const float mo = mrow[qs];
          const float mn = fmaxf(mo, tm);
          const float sc = exp2f(mo - mn);
          mrow[qs] = mn;
          float rs = 0.f;
          #pragma unroll
          for (int ks = 0; ks < 4; ++ks)
            #pragma unroll
            for (int jj = 0; jj < 4; ++jj) {
              p[ks][jj] = exp2f(p[ks][jj] - mn);
              rs += p[ks][jj];
            }
          rs += __shfl_xor(rs, 16, 64);
          rs += __shfl_xor(rs, 32, 64);
          lrow[qs] = lrow[qs]*sc + rs;
          #pragma unroll
          for (int dt = 0; dt < 4; ++dt) o[qs][dt] *= sc;
          #pragma unroll
          for (int ks = 0; ks < 4; ++ks) {
            bf16x4 pw = { (bf16)p[ks][0], (bf16)p[ks][1],
                          (bf16)p[ks][2], (bf16)p[ks][3] };
            *(bf16x4*)&Pb[wv][(qs*16 + c)*64 +
                (((ks*2 + (g >> 1)) ^ (c & 7)) << 3) + ((g & 1) << 2)] = pw;
          }
        }
        asm volatile("s_waitcnt lgkmcnt(0)" ::: "memory");
        __builtin_amdgcn_sched_barrier(0);
        bf16x8 pbf[2][2];
        #pragma unroll
        for (int qs = 0; qs < 2; ++qs)
          #pragma unroll
          for (int kk = 0; kk < 2; ++kk)
            pbf[qs][kk] = *(const bf16x8*)
                &Pb[wv][(qs*16 + c)*64 + (((kk*4 + g) ^ (c & 7)) << 3)];
        __builtin_amdgcn_s_setprio(1);
        #pragma unroll
        for (int dt = 0; dt < 4; ++dt) {
          #pragma unroll
          for (int kk = 0; kk < 2; ++kk) {
            const bf16x8 va = *(const bf16x8*)
                &Vt[cur][(dt*16 + c)*64 +
                         ((((kk*4 + g) ^ (c & 7) ^ (dt << 1)) & 7) << 3)];
            #pragma unroll
            for (int qs = 0; qs < 2; ++qs)
              o[qs][dt] = __builtin_amdgcn_mfma_f32_16x16x32_bf16(
                  va, pbf[qs][kk], o[qs][dt], 0, 0, 0);
          }
        }
        __builtin_amdgcn_s_setprio(0);
      }

      asm volatile("s_waitcnt vmcnt(0)" ::: "memory");
      if (hn) VT_WRITE(nxt);
      __syncthreads();
      cur = nxt;
    }

    #pragma unroll
    for (int qs = 0; qs < 2; ++qs) {
      const float inv = 1.0f / lrow[qs];
      const int q = q0w + qs*16 + c;
      #pragma unroll
      for (int dt = 0; dt < 4; ++dt) {
        const size_t base = ((size_t)n*TT + q)*CC + h*DD + dt*16 + g*4;
        const float4 xv = *(const float4*)(x + base);
        float4 ov;
        ov.x = xv.x + o[qs][dt][0]*inv;
        ov.y = xv.y + o[qs][dt][1]*inv;
        ov.z = xv.z + o[qs][dt][2]*inv;
        ov.w = xv.w + o[qs][dt][3]*inv;
        *(float4*)(out + base) = ov;
      }
    }
  }
  #undef VT_WRITE
}

// ---------------- launcher ----------------
extern "C" void kernel_launch(void* const* d_in, const int* in_sizes, int n_in,
                              void* d_out, int out_size, void* d_ws, size_t ws_size,
                              hipStream_t stream) {
  const float* x    = (const float*)d_in[0];
  const float* ln1w = (const float*)d_in[1];
  const float* ln1b = (const float*)d_in[2];
  const float* wq   = (const float*)d_in[3];
  const float* wk   = (const float*)d_in[4];
  const float* wvv  = (const float*)d_in[5];
  const float* ln2w = (const float*)d_in[6];
  const float* ln2b = (const float*)d_in[7];
  const float* f1w  = (const float*)d_in[8];
  const float* f1b  = (const float*)d_in[9];
  const float* f2w  = (const float*)d_in[10];
  const float* f2b  = (const float*)d_in[11];
  float* out = (float*)d_out;

  bf16* ws     = (bf16*)d_ws;
  bf16* wfused = ws;                   // [wq|wk|wv] (3072x1024)
  bf16* wf1    = ws + 3145728;         // fc1 (4096x1024)
  bf16* wf2    = ws + 7340032;         // fc2 (1024x4096)
  bf16* lnb    = ws + 11534336;        // ln output (8192x1024)
  bf16* big    = ws + 19922944;        // qkv [3][n,h,t,d] then h1
  bf16* h1     = big;

  cvt_kernel<<<2048, 256, 0, stream>>>(wq, wk, wvv, f1w, f2w, wfused);
  ln_kernel<<<MM, 256, 0, stream>>>(x, ln1w, ln1b, lnb);
  gemm8_kernel<0><<<dim3(64, 12), 512, 0, stream>>>(lnb, wfused, 1024, big, nullptr, nullptr);
  attn_kernel<<<512, 256, 0, stream>>>(big, x, out);
  ln_kernel<<<MM, 256, 0, stream>>>(out, ln2w, ln2b, lnb);
  gemm8_kernel<1><<<dim3(64, 16), 512, 0, stream>>>(lnb, wf1, 1024, h1, f1b, nullptr);
  gemm8_kernel<2><<<dim3(64, 4), 512, 0, stream>>>(h1, wf2, 4096, out, f2b, out);
}